// Round 1
// baseline (1283.592 us; speedup 1.0000x reference)
//
#include <hip/hip_runtime.h>
#include <math.h>

#define T      512
#define NBATCH 512
#define IN_DIM 64
#define H      100
#define HP     104   // padded to multiple of 4 floats (16B) for float4 LDS reads

// One block per batch element. Threads 0..127: layer-1 neurons (j = tid).
// Threads 128..255: layer-2 neurons (j = tid-128), pipelined one timestep
// behind layer 1. Weights live in registers (unified w[200] array so the
// two layers' columns share the same 200-VGPR live range instead of
// summing to 364). h state is double-buffered in LDS; one barrier/iter.
__global__ __launch_bounds__(256, 1)
void drnn_kernel(const float* __restrict__ x,
                 const float* __restrict__ W1x, const float* __restrict__ W1h,
                 const float* __restrict__ b1,
                 const float* __restrict__ W2x, const float* __restrict__ W2h,
                 const float* __restrict__ b2,
                 const float* __restrict__ Wo,  const float* __restrict__ bo,
                 float* __restrict__ out)
{
    __shared__ float h1buf[2][HP];
    __shared__ float h2buf[2][HP];
    __shared__ float xbuf[2][IN_DIM];

    const int tid = threadIdx.x;
    const int b   = blockIdx.x;
    const float* __restrict__ xrow = x + (size_t)b * T * IN_DIM;

    // ---- zero-init LDS state (h(-1) = 0) ----
    if (tid < HP) {
        h1buf[0][tid] = 0.f; h1buf[1][tid] = 0.f;
        h2buf[0][tid] = 0.f; h2buf[1][tid] = 0.f;
    }
    if (tid < IN_DIM) xbuf[0][tid] = xrow[tid];   // x(0)

    const bool isL1 = (tid < 128);
    const int  j    = isL1 ? tid : (tid - 128);
    const bool act  = (j < H);

    // ---- per-thread weight column in registers (unified array) ----
    // L1 thread: w[0:64]   = W1x[:,j], w[64:164] = W1h[:,j]
    // L2 thread: w[0:100]  = W2x[:,j], w[100:200]= W2h[:,j]
    float w[2 * H];
    #pragma unroll
    for (int k = 0; k < 2 * H; ++k) w[k] = 0.f;
    float bj = 0.f;

    if (isL1) {
        if (act) {
            #pragma unroll
            for (int k = 0; k < IN_DIM; ++k) w[k] = W1x[k * H + j];
            #pragma unroll
            for (int k = 0; k < H; ++k) w[IN_DIM + k] = W1h[k * H + j];
            bj = b1[j];
        }
    } else {
        if (act) {
            #pragma unroll
            for (int k = 0; k < H; ++k) w[k] = W2x[k * H + j];
            #pragma unroll
            for (int k = 0; k < H; ++k) w[H + k] = W2h[k * H + j];
            bj = b2[j];
        }
    }

    // ---- x register pipeline (wave 0): xr1 loaded 2+ iters ahead ----
    float xr0 = 0.f, xr1 = 0.f;
    if (tid < 64) {
        xr0 = xrow[1 * IN_DIM + tid];   // x(1)
        xr1 = xrow[2 * IN_DIM + tid];   // x(2)
    }

    __syncthreads();

    float h1n = 0.f, h2n = 0.f;

    // Iter i: L1 computes h1(i) (i<T); L2 computes h2(i-1) (i>=1).
    // Reads hit buffers written in earlier iterations; writes go to the
    // complementary buffer -> a single barrier per iteration suffices.
    #pragma unroll 1
    for (int i = 0; i <= T; ++i) {
        const int p = i & 1;       // write slot for h1(i) / read slot h2(i-2)
        const int q = p ^ 1;       // read slot h1(i-1) / write slot h2(i-1)

        if (isL1) {
            if (i < T && act) {
                float a0 = bj, a1 = 0.f, a2 = 0.f, a3 = 0.f;
                const float4* xv = (const float4*)xbuf[p];
                #pragma unroll
                for (int c = 0; c < IN_DIM / 4; ++c) {
                    float4 v = xv[c];
                    a0 += v.x * w[4*c+0]; a1 += v.y * w[4*c+1];
                    a2 += v.z * w[4*c+2]; a3 += v.w * w[4*c+3];
                }
                const float4* hv = (const float4*)h1buf[q];
                #pragma unroll
                for (int c = 0; c < H / 4; ++c) {
                    float4 v = hv[c];
                    a0 += v.x * w[IN_DIM + 4*c+0]; a1 += v.y * w[IN_DIM + 4*c+1];
                    a2 += v.z * w[IN_DIM + 4*c+2]; a3 += v.w * w[IN_DIM + 4*c+3];
                }
                h1n = tanhf((a0 + a1) + (a2 + a3));
            }
            // x staging: write x(i+1) for next iter; refill 3 ahead (2-iter cover)
            if (tid < 64) {
                xbuf[q][tid] = xr0;
                xr0 = xr1;
                if (i + 3 < T) xr1 = xrow[(size_t)(i + 3) * IN_DIM + tid];
            }
        } else {
            if (i >= 1 && act) {
                float a0 = bj, a1 = 0.f, a2 = 0.f, a3 = 0.f;
                const float4* hv = (const float4*)h1buf[q];   // h1(i-1)
                #pragma unroll
                for (int c = 0; c < H / 4; ++c) {
                    float4 v = hv[c];
                    a0 += v.x * w[4*c+0]; a1 += v.y * w[4*c+1];
                    a2 += v.z * w[4*c+2]; a3 += v.w * w[4*c+3];
                }
                const float4* gv = (const float4*)h2buf[p];   // h2(i-2)
                #pragma unroll
                for (int c = 0; c < H / 4; ++c) {
                    float4 v = gv[c];
                    a0 += v.x * w[H + 4*c+0]; a1 += v.y * w[H + 4*c+1];
                    a2 += v.z * w[H + 4*c+2]; a3 += v.w * w[H + 4*c+3];
                }
                h2n = tanhf((a0 + a1) + (a2 + a3));
            }
        }

        // writes target buffers nobody reads this iteration
        if (isL1) { if (i < T && act)  h1buf[p][j] = h1n; }
        else      { if (i >= 1 && act) h2buf[q][j] = h2n; }
        __syncthreads();
    }

    // ---- epilogue: h1(T-1) in h1buf[(T-1)&1], h2(T-1) in h2buf[(T-1)&1] ----
    const int pT = (T - 1) & 1;
    if (isL1 && act)
        out[NBATCH + (size_t)b * H + j] = h1buf[pT][j];
    if (!isL1 && act)
        out[NBATCH + (size_t)NBATCH * H + (size_t)b * H + j] = h2buf[pT][j];

    // out[b] = h2_T . Wo + bo  (wave-0 shuffle reduction)
    if (tid < 64) {
        float v = h2buf[pT][tid] * Wo[tid];
        if (tid + 64 < H) v += h2buf[pT][tid + 64] * Wo[tid + 64];
        #pragma unroll
        for (int off = 32; off >= 1; off >>= 1) v += __shfl_down(v, off);
        if (tid == 0) out[b] = v + bo[0];
    }
}

extern "C" void kernel_launch(void* const* d_in, const int* in_sizes, int n_in,
                              void* d_out, int out_size, void* d_ws, size_t ws_size,
                              hipStream_t stream) {
    const float* x   = (const float*)d_in[0];
    const float* W1x = (const float*)d_in[1];
    const float* W1h = (const float*)d_in[2];
    const float* b1  = (const float*)d_in[3];
    const float* W2x = (const float*)d_in[4];
    const float* W2h = (const float*)d_in[5];
    const float* b2  = (const float*)d_in[6];
    const float* Wo  = (const float*)d_in[7];
    const float* bo  = (const float*)d_in[8];
    float* out = (float*)d_out;

    drnn_kernel<<<NBATCH, 256, 0, stream>>>(x, W1x, W1h, b1, W2x, W2h, b2,
                                            Wo, bo, out);
}